// Round 10
// baseline (205.151 us; speedup 1.0000x reference)
//
#include <hip/hip_runtime.h>
#include <stdint.h>

// Problem constants
#define NB   32
#define NCH  256
#define NPIX 3136      // 56*56
#define PH   58        // padded width/height (56+2)
#define PPIX 3364      // 58*58
#define NCOL 100352    // NB*NPIX

typedef __bf16 bf16x8 __attribute__((ext_vector_type(8)));
typedef float  f32x4  __attribute__((ext_vector_type(4)));

__device__ __forceinline__ unsigned short f2bf(float f) {
  unsigned int u = __float_as_uint(f);
  u += 0x7fff + ((u >> 16) & 1);           // RNE
  return (unsigned short)(u >> 16);
}
__device__ __forceinline__ float bf2f(unsigned int us) {
  return __uint_as_float(us << 16);
}

// async global->LDS, 16B per lane. LDS ptr must be wave-uniform; HW adds lane*16.
__device__ __forceinline__ void gload_lds16(const void* g, void* l) {
  __builtin_amdgcn_global_load_lds(
      (const __attribute__((address_space(1))) unsigned int*)(uintptr_t)g,
      (__attribute__((address_space(3))) unsigned int*)(unsigned int)(uintptr_t)l,
      16, 0, 0);
}

// ---------------- prep: weight tiles + zero xT borders (fused, independent work) ----------------
// wt layout: [stage=cs*9+tap][co 256][slot 4][e 8] bf16, with bank-swizzle baked in:
// LDS slot s holds global ci-slot (s ^ ((co>>1)&3)).
__global__ __launch_bounds__(256) void prep_k(const float* __restrict__ cw,
                                              unsigned short* __restrict__ wt,
                                              unsigned short* __restrict__ xT) {
  int blk = blockIdx.x;
  int tid = threadIdx.x;
  if (blk < 144) {
    int stage = blk >> 1, half = blk & 1;
    int tap = stage % 9, cs = stage / 9;
    unsigned short* dst = wt + (size_t)stage * 8192 + half * 4096;
#pragma unroll
    for (int e8 = 0; e8 < 16; ++e8) {
      int j = e8 * 256 + tid;           // 0..4095 over [128co][32ci]
      int ci_l = j & 31, co_l = j >> 5;
      int slot = ci_l >> 3, e = ci_l & 7;
      int slot_g = slot ^ ((co_l >> 1) & 3);        // inverse swizzle at source
      int co = half * 128 + co_l, ci = cs * 32 + slot_g * 8 + e;
      dst[j] = f2bf(cw[((size_t)co * 256 + ci) * 9 + tap]);
    }
  } else {
    int g = (blk - 144) * 256 + tid;    // uint index, < 933888
    int b = g / 29184;                   // 228 border rows * 128 uints
    int rem = g - b * 29184;
    int ridx = rem >> 7, ui = rem & 127;
    int row;
    if (ridx < 58)       row = ridx;
    else if (ridx < 116) row = 57 * 58 + (ridx - 58);
    else { int r2 = ridx - 116; row = (1 + (r2 >> 1)) * 58 + ((r2 & 1) ? 57 : 0); }
    ((unsigned int*)(xT + ((size_t)b * PPIX + row) * NCH))[ui] = 0;
  }
}

// ---------------- transpose x [b][ci][pix] fp32 -> xT [b][padpix][ci] bf16, + partial pooling ----------------
__global__ __launch_bounds__(256) void transpose_x(const float* __restrict__ x,
                                                   unsigned short* __restrict__ xT,
                                                   float* __restrict__ pp2) {
  int pblk = blockIdx.x, ciblk = blockIdx.y, b = blockIdx.z;
  int p0 = pblk * 64, ci0 = ciblk * 64;
  __shared__ unsigned short t[64][65];
  int tid = threadIdx.x;
  int pq = tid & 15, cq = tid >> 4;
  const float* xb = x + ((size_t)b * NCH + ci0) * NPIX + p0;
#pragma unroll
  for (int pass = 0; pass < 4; ++pass) {
    int ci_l = pass * 16 + cq;
    float4 v = *(const float4*)&xb[(size_t)ci_l * NPIX + pq * 4];
    t[ci_l][pq * 4 + 0] = f2bf(v.x);
    t[ci_l][pq * 4 + 1] = f2bf(v.y);
    t[ci_l][pq * 4 + 2] = f2bf(v.z);
    t[ci_l][pq * 4 + 3] = f2bf(v.w);
  }
  __syncthreads();
  if (tid < 64) {
    float s = 0;
#pragma unroll
    for (int p = 0; p < 64; ++p) s += bf2f(t[tid][p]);
    pp2[((size_t)b * 49 + pblk) * 256 + ci0 + tid] = s;
  }
  int cio = (tid & 31) * 2, jo = tid >> 5;
#pragma unroll
  for (int pass = 0; pass < 8; ++pass) {
    int jj = pass * 8 + jo;
    int p = p0 + jj;
    int h = p / 56, w = p % 56;
    int row = (h + 1) * PH + (w + 1);
    unsigned int v = (unsigned int)t[cio][jj] | ((unsigned int)t[cio + 1][jj] << 16);
    *(unsigned int*)(xT + ((size_t)b * PPIX + row) * NCH + ci0 + cio) = v;
  }
}

// ---------------- head: rmsnorm + phi + sigmoids + sinkhorn -> 3 scalars per batch ----------------
__global__ __launch_bounds__(256) void head_k(const float* __restrict__ pp2,
    const float* __restrict__ phi_w, const float* __restrict__ phi_b,
    const float* __restrict__ rms_w, const float* __restrict__ a_pre,
    const float* __restrict__ a_post, const float* __restrict__ a_res,
    float* __restrict__ scales) {
  int b = blockIdx.x;
  int t = threadIdx.x;
  __shared__ float red[4];
  __shared__ float coeff[24];
  float s = 0;
  for (int ch = 0; ch < 49; ++ch) s += pp2[((size_t)b * 49 + ch) * 256 + t];
  float pooled = s * (1.0f / (float)NPIX);
  float v = pooled * pooled;
#pragma unroll
  for (int off = 32; off; off >>= 1) v += __shfl_down(v, off);
  if ((t & 63) == 0) red[t >> 6] = v;
  __syncthreads();
  float ms = (red[0] + red[1] + red[2] + red[3]) * (1.0f / 256.0f);
  float inv = rsqrtf(ms + 1e-20f);
  __syncthreads();
  for (int o = 0; o < 24; ++o) {
    float ws_ = 0;
#pragma unroll
    for (int i = 0; i < 4; ++i) ws_ += phi_w[(size_t)o * 1024 + i * 256 + t] * rms_w[i * 256 + t];
    float c = pooled * ws_;
#pragma unroll
    for (int off = 32; off; off >>= 1) c += __shfl_down(c, off);
    if ((t & 63) == 0) red[t >> 6] = c;
    __syncthreads();
    if (t == 0) coeff[o] = inv * (red[0] + red[1] + red[2] + red[3]) + phi_b[o];
    __syncthreads();
  }
  if (t == 0) {
    float ap = a_pre[0], apo = a_post[0], ar = a_res[0];
    float spre = 0, psum = 0;
#pragma unroll
    for (int i = 0; i < 4; ++i) {
      spre += 1.0f / (1.0f + expf(-ap * coeff[i]));
      psum += 2.0f / (1.0f + expf(-apo * coeff[4 + i]));
    }
    float M[4][4];
#pragma unroll
    for (int i = 0; i < 4; ++i)
#pragma unroll
      for (int j = 0; j < 4; ++j) M[i][j] = expf(ar * coeff[8 + i * 4 + j]);
    for (int it = 0; it < 20; ++it) {
#pragma unroll
      for (int i = 0; i < 4; ++i) {
        float rs = M[i][0] + M[i][1] + M[i][2] + M[i][3];
        float rr = 1.0f / rs;
        M[i][0] *= rr; M[i][1] *= rr; M[i][2] *= rr; M[i][3] *= rr;
      }
#pragma unroll
      for (int j = 0; j < 4; ++j) {
        float cs2 = M[0][j] + M[1][j] + M[2][j] + M[3][j];
        float rr = 1.0f / cs2;
        M[0][j] *= rr; M[1][j] *= rr; M[2][j] *= rr; M[3][j] *= rr;
      }
    }
    float r = 0.25f * (M[0][0] + M[1][1] + M[2][2] + M[3][3]);
    float pm = 0.25f * psum;
    scales[b * 4 + 0] = r;          // on x
    scales[b * 4 + 1] = pm * spre;  // on conv(x)
    scales[b * 4 + 2] = pm;         // on conv_b
  }
}

// ---------------- conv implicit GEMM: faithful m201 8-phase port.
// 256co x 256col tile, 392 blocks, 512 thr / 8 waves (2M x 4N), MFMA 16x16x32.
// K stream = 144 half-tiles (16 KB each: A or B of one K32 stage), 1 staged per phase
// at lag 6; uniform counted vmcnt(8) mid-phase (peeled tail: 8,8,8,4 / 4,0,0,0).
// Per phase: {ds_read quadrant ; stage half ; vmcnt ; barrier ; lgkmcnt(0) ;
//             sched_barrier ; setprio(1) ; 16 MFMA ; setprio(0) ; barrier}.
// Buffer = 64 KB [Ak0|Ak1|Bk0|Bk1], dbuf by K64-tile. XOR bank swizzle (0 conflicts). ----------------
__global__ __launch_bounds__(512, 2) void conv_k(
    const unsigned short* __restrict__ xT, const unsigned short* __restrict__ wt,
    const float* __restrict__ x, const float* __restrict__ conv_b,
    const float* __restrict__ scales, float* __restrict__ out) {
  __shared__ __align__(16) char lds_[2][65536];
  const int colblk = blockIdx.x;      // 392
  const int tid = threadIdx.x;
  const int wv = tid >> 6, l = tid & 63;
  const int wm = wv >> 2, wn = wv & 3;

  // ---- B staging lane addresses (2 gloads per half: 16 cols x 64B each) ----
  const char* laneB0;
  const char* laneB1;
  {
    const char* lb[2];
#pragma unroll
    for (int gi = 0; gi < 2; ++gi) {
      int col_local = wv * 32 + gi * 16 + (l >> 2);
      int col = colblk * 256 + col_local;
      int bb = col / NPIX, pix = col - bb * NPIX;
      int prow = (pix / 56 + 1) * PH + (pix % 56 + 1);
      int slot_g = (l & 3) ^ ((col_local >> 1) & 3);
      lb[gi] = (const char*)xT + ((size_t)bb * PPIX + prow) * 512 + slot_g * 16;
    }
    laneB0 = lb[0]; laneB1 = lb[1];
  }
  const char* wtb = (const char*)wt;
  // tap -> padded-row byte shift
  const int tapsh[9] = {-59 * 512, -58 * 512, -57 * 512, -512, 0, 512, 57 * 512, 58 * 512, 59 * 512};

  // stage one 16KB half-tile (A from wt, or B from xT) for K32 stage ST
#define STG_A(DST, ST) do {                                                 \
    const char* s_ = wtb + (size_t)(ST) * 16384 + wv * 2048 + l * 16;       \
    char* d_ = (char*)(DST) + wv * 2048;                                    \
    gload_lds16(s_, d_); gload_lds16(s_ + 1024, d_ + 1024);                 \
  } while (0)
#define STG_B(DST, ST) do {                                                 \
    int cs_ = (ST) / 9, tap_ = (ST) - cs_ * 9;                              \
    int sh_ = tapsh[tap_] + cs_ * 64;                                       \
    char* d_ = (char*)(DST) + wv * 2048;                                    \
    gload_lds16(laneB0 + sh_, d_); gload_lds16(laneB1 + sh_, d_ + 1024);    \
  } while (0)

  // ---- fragment LDS byte offsets (bank-swizzled: slot ^= (row>>1)&3) ----
  int aoff[8], boff[4];
#pragma unroll
  for (int m = 0; m < 8; ++m) {
    int row = wm * 128 + m * 16 + (l & 15);
    aoff[m] = row * 64 + ((((l >> 4) ^ (row >> 1)) & 3) << 4);
  }
#pragma unroll
  for (int n = 0; n < 4; ++n) {
    int row = wn * 64 + n * 16 + (l & 15);
    boff[n] = 32768 + row * 64 + ((((l >> 4) ^ (row >> 1)) & 3) << 4);
  }

  f32x4 acc[8][4];
#pragma unroll
  for (int m = 0; m < 8; ++m)
#pragma unroll
    for (int n = 0; n < 4; ++n) acc[m][n] = (f32x4){0.f, 0.f, 0.f, 0.f};

#define MFMA16(MH)                                                                         \
    acc[(MH)*4+0][0] = __builtin_amdgcn_mfma_f32_16x16x32_bf16(a0, b0, acc[(MH)*4+0][0], 0,0,0); \
    acc[(MH)*4+0][1] = __builtin_amdgcn_mfma_f32_16x16x32_bf16(a0, b1, acc[(MH)*4+0][1], 0,0,0); \
    acc[(MH)*4+0][2] = __builtin_amdgcn_mfma_f32_16x16x32_bf16(a0, b2, acc[(MH)*4+0][2], 0,0,0); \
    acc[(MH)*4+0][3] = __builtin_amdgcn_mfma_f32_16x16x32_bf16(a0, b3, acc[(MH)*4+0][3], 0,0,0); \
    acc[(MH)*4+1][0] = __builtin_amdgcn_mfma_f32_16x16x32_bf16(a1, b0, acc[(MH)*4+1][0], 0,0,0); \
    acc[(MH)*4+1][1] = __builtin_amdgcn_mfma_f32_16x16x32_bf16(a1, b1, acc[(MH)*4+1][1], 0,0,0); \
    acc[(MH)*4+1][2] = __builtin_amdgcn_mfma_f32_16x16x32_bf16(a1, b2, acc[(MH)*4+1][2], 0,0,0); \
    acc[(MH)*4+1][3] = __builtin_amdgcn_mfma_f32_16x16x32_bf16(a1, b3, acc[(MH)*4+1][3], 0,0,0); \
    acc[(MH)*4+2][0] = __builtin_amdgcn_mfma_f32_16x16x32_bf16(a2, b0, acc[(MH)*4+2][0], 0,0,0); \
    acc[(MH)*4+2][1] = __builtin_amdgcn_mfma_f32_16x16x32_bf16(a2, b1, acc[(MH)*4+2][1], 0,0,0); \
    acc[(MH)*4+2][2] = __builtin_amdgcn_mfma_f32_16x16x32_bf16(a2, b2, acc[(MH)*4+2][2], 0,0,0); \
    acc[(MH)*4+2][3] = __builtin_amdgcn_mfma_f32_16x16x32_bf16(a2, b3, acc[(MH)*4+2][3], 0,0,0); \
    acc[(MH)*4+3][0] = __builtin_amdgcn_mfma_f32_16x16x32_bf16(a3, b0, acc[(MH)*4+3][0], 0,0,0); \
    acc[(MH)*4+3][1] = __builtin_amdgcn_mfma_f32_16x16x32_bf16(a3, b1, acc[(MH)*4+3][1], 0,0,0); \
    acc[(MH)*4+3][2] = __builtin_amdgcn_mfma_f32_16x16x32_bf16(a3, b2, acc[(MH)*4+3][2], 0,0,0); \
    acc[(MH)*4+3][3] = __builtin_amdgcn_mfma_f32_16x16x32_bf16(a3, b3, acc[(MH)*4+3][3], 0,0,0)

#define PHASE(MH, KO, STG_STMT, VM_ASM) do {                                   \
    if ((MH) == 0) {                                                           \
      b0 = *(const bf16x8*)(Ab + (KO) + boff[0]);                              \
      b1 = *(const bf16x8*)(Ab + (KO) + boff[1]);                              \
      b2 = *(const bf16x8*)(Ab + (KO) + boff[2]);                              \
      b3 = *(const bf16x8*)(Ab + (KO) + boff[3]);                              \
    }                                                                          \
    a0 = *(const bf16x8*)(Ab + (KO) + aoff[(MH)*4+0]);                         \
    a1 = *(const bf16x8*)(Ab + (KO) + aoff[(MH)*4+1]);                         \
    a2 = *(const bf16x8*)(Ab + (KO) + aoff[(MH)*4+2]);                         \
    a3 = *(const bf16x8*)(Ab + (KO) + aoff[(MH)*4+3]);                         \
    STG_STMT;                                                                  \
    asm volatile(VM_ASM ::: "memory");                                         \
    __builtin_amdgcn_s_barrier();                                              \
    asm volatile("s_waitcnt lgkmcnt(0)" ::: "memory");                         \
    __builtin_amdgcn_sched_barrier(0);                                         \
    __builtin_amdgcn_s_setprio(1);                                             \
    MFMA16(MH);                                                                \
    __builtin_amdgcn_s_setprio(0);                                             \
    __builtin_amdgcn_s_barrier();                                              \
  } while (0)

  // ---- prologue: halves 0..5 in FIFO order (K-tile0 full + K-tile1 k0) ----
  STG_A(&lds_[0][0],         0);
  STG_B(&lds_[0][0] + 32768, 0);
  STG_A(&lds_[0][0] + 16384, 1);
  STG_B(&lds_[0][0] + 49152, 1);
  STG_A(&lds_[1][0],         2);
  STG_B(&lds_[1][0] + 32768, 2);
  asm volatile("s_waitcnt vmcnt(8)" ::: "memory");   // halves 0,1 landed
  __builtin_amdgcn_s_barrier();

  // ---- main: K-tiles 0..33 with lag-6 staging ----
  for (int s = 0; s < 34; ++s) {
    const char* Ab = &lds_[s & 1][0];
    char* nbuf = &lds_[(s + 1) & 1][0];
    char* cbuf = &lds_[s & 1][0];
    const int stn = 2 * s + 3, stc = 2 * s + 4;
    bf16x8 a0, a1, a2, a3, b0, b1, b2, b3;
    PHASE(0, 0,     STG_A(nbuf + 16384, stn), "s_waitcnt vmcnt(8)");
    PHASE(1, 0,     STG_B(nbuf + 49152, stn), "s_waitcnt vmcnt(8)");
    PHASE(0, 16384, STG_A(cbuf,         stc), "s_waitcnt vmcnt(8)");
    PHASE(1, 16384, STG_B(cbuf + 32768, stc), "s_waitcnt vmcnt(8)");
  }
  { // K-tile 34 (buf0): stages 71 only; tail vmcnt begins
    const char* Ab = &lds_[0][0];
    char* nbuf = &lds_[1][0];
    bf16x8 a0, a1, a2, a3, b0, b1, b2, b3;
    PHASE(0, 0,     STG_A(nbuf + 16384, 71), "s_waitcnt vmcnt(8)");
    PHASE(1, 0,     STG_B(nbuf + 49152, 71), "s_waitcnt vmcnt(8)");
    PHASE(0, 16384, (void)0,                 "s_waitcnt vmcnt(8)");
    PHASE(1, 16384, (void)0,                 "s_waitcnt vmcnt(4)");
  }
  { // K-tile 35 (buf1): drain
    const char* Ab = &lds_[1][0];
    bf16x8 a0, a1, a2, a3, b0, b1, b2, b3;
    PHASE(0, 0,     (void)0, "s_waitcnt vmcnt(4)");
    PHASE(1, 0,     (void)0, "s_waitcnt vmcnt(0)");
    PHASE(0, 16384, (void)0, "s_waitcnt vmcnt(0)");
    PHASE(1, 16384, (void)0, "s_waitcnt vmcnt(0)");
  }
#undef PHASE
#undef MFMA16
#undef STG_A
#undef STG_B

  // ---- epilogue: out = sX*x + sY*conv + sB*conv_b ----
  const int lc = l & 15, lg = l >> 4;
  float sXn[4], sYn[4], sBn[4];
  size_t obase[4];
#pragma unroll
  for (int n = 0; n < 4; ++n) {
    int col = colblk * 256 + wn * 64 + n * 16 + lc;
    int bb = col / NPIX, pix = col - bb * NPIX;
    sXn[n] = scales[bb * 4 + 0];
    sYn[n] = scales[bb * 4 + 1];
    sBn[n] = scales[bb * 4 + 2];
    obase[n] = (size_t)bb * NCH * NPIX + pix;
  }
#pragma unroll
  for (int m = 0; m < 8; ++m) {
#pragma unroll
    for (int j = 0; j < 4; ++j) {
      int co = wm * 128 + m * 16 + lg * 4 + j;
      float cbv = conv_b[co];
      size_t cooff = (size_t)co * NPIX;
#pragma unroll
      for (int n = 0; n < 4; ++n) {
        size_t idx = obase[n] + cooff;
        out[idx] = sXn[n] * x[idx] + sYn[n] * acc[m][n][j] + sBn[n] * cbv;
      }
    }
  }
}

extern "C" void kernel_launch(void* const* d_in, const int* in_sizes, int n_in,
                              void* d_out, int out_size, void* d_ws, size_t ws_size,
                              hipStream_t stream) {
  const float* x      = (const float*)d_in[0];
  const float* phi_w  = (const float*)d_in[1];
  const float* phi_b  = (const float*)d_in[2];
  const float* rms_w  = (const float*)d_in[3];
  const float* a_pre  = (const float*)d_in[4];
  const float* a_post = (const float*)d_in[5];
  const float* a_res  = (const float*)d_in[6];
  const float* conv_w = (const float*)d_in[7];
  const float* conv_b = (const float*)d_in[8];
  float* out = (float*)d_out;

  char* ws = (char*)d_ws;
  unsigned short* xT = (unsigned short*)ws;
  const size_t XT_BYTES = (size_t)NB * PPIX * NCH * 2;            // 55,115,776
  float* pp2 = (float*)(ws + XT_BYTES);
  const size_t PP_BYTES = (size_t)NB * 49 * 256 * 4;              // 1,605,632
  float* scales = (float*)(ws + XT_BYTES + PP_BYTES);
  unsigned short* wt = (unsigned short*)(ws + XT_BYTES + PP_BYTES + 512);

  prep_k<<<dim3(144 + 3648), dim3(256), 0, stream>>>(conv_w, wt, xT);
  transpose_x<<<dim3(49, 4, NB), dim3(256), 0, stream>>>(x, xT, pp2);
  head_k<<<dim3(NB), dim3(256), 0, stream>>>(pp2, phi_w, phi_b, rms_w, a_pre, a_post, a_res, scales);
  conv_k<<<dim3(392), dim3(512), 0, stream>>>(xT, wt, x, conv_b, scales, out);
}

// Round 11
// 201.433 us; speedup vs baseline: 1.0185x; 1.0185x over previous
//
#include <hip/hip_runtime.h>
#include <stdint.h>

// Problem constants
#define NB   32
#define NCH  256
#define NPIX 3136      // 56*56
#define PH   58        // padded width/height (56+2)
#define PPIX 3364      // 58*58
#define NCOL 100352    // NB*NPIX

typedef __bf16 bf16x8 __attribute__((ext_vector_type(8)));
typedef float  f32x4  __attribute__((ext_vector_type(4)));

__device__ __forceinline__ unsigned short f2bf(float f) {
  unsigned int u = __float_as_uint(f);
  u += 0x7fff + ((u >> 16) & 1);           // RNE
  return (unsigned short)(u >> 16);
}
__device__ __forceinline__ float bf2f(unsigned int us) {
  return __uint_as_float(us << 16);
}

// async global->LDS, 16B per lane. LDS ptr must be wave-uniform; HW adds lane*16.
__device__ __forceinline__ void gload_lds16(const void* g, void* l) {
  __builtin_amdgcn_global_load_lds(
      (const __attribute__((address_space(1))) unsigned int*)(uintptr_t)g,
      (__attribute__((address_space(3))) unsigned int*)(unsigned int)(uintptr_t)l,
      16, 0, 0);
}

// ---------------- prep: weight tiles + zero xT borders (fused, independent work) ----------------
// wt layout: [stage=cs*9+tap][co 256][slot 4][e 8] bf16, with bank-swizzle baked in:
// LDS slot s holds global ci-slot (s ^ (((co&127)>>1)&3)).
__global__ __launch_bounds__(256) void prep_k(const float* __restrict__ cw,
                                              unsigned short* __restrict__ wt,
                                              unsigned short* __restrict__ xT) {
  int blk = blockIdx.x;
  int tid = threadIdx.x;
  if (blk < 144) {
    int stage = blk >> 1, half = blk & 1;
    int tap = stage % 9, cs = stage / 9;
    unsigned short* dst = wt + (size_t)stage * 8192 + half * 4096;
#pragma unroll
    for (int e8 = 0; e8 < 16; ++e8) {
      int j = e8 * 256 + tid;           // 0..4095 over [128co][32ci]
      int ci_l = j & 31, co_l = j >> 5;
      int slot = ci_l >> 3, e = ci_l & 7;
      int slot_g = slot ^ ((co_l >> 1) & 3);        // inverse swizzle at source
      int co = half * 128 + co_l, ci = cs * 32 + slot_g * 8 + e;
      dst[j] = f2bf(cw[((size_t)co * 256 + ci) * 9 + tap]);
    }
  } else {
    int g = (blk - 144) * 256 + tid;    // uint index, < 933888
    int b = g / 29184;                   // 228 border rows * 128 uints
    int rem = g - b * 29184;
    int ridx = rem >> 7, ui = rem & 127;
    int row;
    if (ridx < 58)       row = ridx;
    else if (ridx < 116) row = 57 * 58 + (ridx - 58);
    else { int r2 = ridx - 116; row = (1 + (r2 >> 1)) * 58 + ((r2 & 1) ? 57 : 0); }
    ((unsigned int*)(xT + ((size_t)b * PPIX + row) * NCH))[ui] = 0;
  }
}

// ---------------- transpose x [b][ci][pix] fp32 -> xT [b][padpix][ci] bf16, + partial pooling ----------------
__global__ __launch_bounds__(256) void transpose_x(const float* __restrict__ x,
                                                   unsigned short* __restrict__ xT,
                                                   float* __restrict__ pp2) {
  int pblk = blockIdx.x, ciblk = blockIdx.y, b = blockIdx.z;
  int p0 = pblk * 64, ci0 = ciblk * 64;
  __shared__ unsigned short t[64][65];
  int tid = threadIdx.x;
  int pq = tid & 15, cq = tid >> 4;
  const float* xb = x + ((size_t)b * NCH + ci0) * NPIX + p0;
#pragma unroll
  for (int pass = 0; pass < 4; ++pass) {
    int ci_l = pass * 16 + cq;
    float4 v = *(const float4*)&xb[(size_t)ci_l * NPIX + pq * 4];
    t[ci_l][pq * 4 + 0] = f2bf(v.x);
    t[ci_l][pq * 4 + 1] = f2bf(v.y);
    t[ci_l][pq * 4 + 2] = f2bf(v.z);
    t[ci_l][pq * 4 + 3] = f2bf(v.w);
  }
  __syncthreads();
  if (tid < 64) {
    float s = 0;
#pragma unroll
    for (int p = 0; p < 64; ++p) s += bf2f(t[tid][p]);
    pp2[((size_t)b * 49 + pblk) * 256 + ci0 + tid] = s;
  }
  int cio = (tid & 31) * 2, jo = tid >> 5;
#pragma unroll
  for (int pass = 0; pass < 8; ++pass) {
    int jj = pass * 8 + jo;
    int p = p0 + jj;
    int h = p / 56, w = p % 56;
    int row = (h + 1) * PH + (w + 1);
    unsigned int v = (unsigned int)t[cio][jj] | ((unsigned int)t[cio + 1][jj] << 16);
    *(unsigned int*)(xT + ((size_t)b * PPIX + row) * NCH + ci0 + cio) = v;
  }
}

// ---------------- head: rmsnorm + phi + sigmoids + sinkhorn -> 3 scalars per batch ----------------
__global__ __launch_bounds__(256) void head_k(const float* __restrict__ pp2,
    const float* __restrict__ phi_w, const float* __restrict__ phi_b,
    const float* __restrict__ rms_w, const float* __restrict__ a_pre,
    const float* __restrict__ a_post, const float* __restrict__ a_res,
    float* __restrict__ scales) {
  int b = blockIdx.x;
  int t = threadIdx.x;
  __shared__ float red[4];
  __shared__ float coeff[24];
  float s = 0;
  for (int ch = 0; ch < 49; ++ch) s += pp2[((size_t)b * 49 + ch) * 256 + t];
  float pooled = s * (1.0f / (float)NPIX);
  float v = pooled * pooled;
#pragma unroll
  for (int off = 32; off; off >>= 1) v += __shfl_down(v, off);
  if ((t & 63) == 0) red[t >> 6] = v;
  __syncthreads();
  float ms = (red[0] + red[1] + red[2] + red[3]) * (1.0f / 256.0f);
  float inv = rsqrtf(ms + 1e-20f);
  __syncthreads();
  for (int o = 0; o < 24; ++o) {
    float ws_ = 0;
#pragma unroll
    for (int i = 0; i < 4; ++i) ws_ += phi_w[(size_t)o * 1024 + i * 256 + t] * rms_w[i * 256 + t];
    float c = pooled * ws_;
#pragma unroll
    for (int off = 32; off; off >>= 1) c += __shfl_down(c, off);
    if ((t & 63) == 0) red[t >> 6] = c;
    __syncthreads();
    if (t == 0) coeff[o] = inv * (red[0] + red[1] + red[2] + red[3]) + phi_b[o];
    __syncthreads();
  }
  if (t == 0) {
    float ap = a_pre[0], apo = a_post[0], ar = a_res[0];
    float spre = 0, psum = 0;
#pragma unroll
    for (int i = 0; i < 4; ++i) {
      spre += 1.0f / (1.0f + expf(-ap * coeff[i]));
      psum += 2.0f / (1.0f + expf(-apo * coeff[4 + i]));
    }
    float M[4][4];
#pragma unroll
    for (int i = 0; i < 4; ++i)
#pragma unroll
      for (int j = 0; j < 4; ++j) M[i][j] = expf(ar * coeff[8 + i * 4 + j]);
    for (int it = 0; it < 20; ++it) {
#pragma unroll
      for (int i = 0; i < 4; ++i) {
        float rs = M[i][0] + M[i][1] + M[i][2] + M[i][3];
        float rr = 1.0f / rs;
        M[i][0] *= rr; M[i][1] *= rr; M[i][2] *= rr; M[i][3] *= rr;
      }
#pragma unroll
      for (int j = 0; j < 4; ++j) {
        float cs2 = M[0][j] + M[1][j] + M[2][j] + M[3][j];
        float rr = 1.0f / cs2;
        M[0][j] *= rr; M[1][j] *= rr; M[2][j] *= rr; M[3][j] *= rr;
      }
    }
    float r = 0.25f * (M[0][0] + M[1][1] + M[2][2] + M[3][3]);
    float pm = 0.25f * psum;
    scales[b * 4 + 0] = r;          // on x
    scales[b * 4 + 1] = pm * spre;  // on conv(x)
    scales[b * 4 + 2] = pm;         // on conv_b
  }
}

// ---------------- conv implicit GEMM: m97-replica config for HIGH RESIDENCY.
// 128co x 128col tile, 256 thr / 4 waves (2M x 2N), acc 64 regs/thread,
// launch_bounds(256,3) -> 3 waves/SIMD = 3 co-resident blocks/CU (12 waves/CU, m97's
// measured sweet spot); LDS 32 KB/block (dbuf 16 KB: A 8K + B 8K).
// Simple 2-phase dbuf K-loop; inter-BLOCK wave overlap (m114) supplies the pipelining
// that intra-block schedules could not (R4/5/6/9/10 all ~160 us at 1 block/CU).
// Grid 784 col-tiles x 2 co-halves = 1568 blocks. XOR bank swizzle (0 conflicts). ----------------
__global__ __launch_bounds__(256, 3) void conv_k(
    const unsigned short* __restrict__ xT, const unsigned short* __restrict__ wt,
    const float* __restrict__ x, const float* __restrict__ conv_b,
    const float* __restrict__ scales, float* __restrict__ out) {
  // per buffer: [A 8 KB: 128co x 32ci][B 8 KB: 128col x 32ci]
  __shared__ __align__(16) char lds_[2][16384];
  const int colblk = blockIdx.x;      // 784
  const int coh = blockIdx.y;         // 2 (co half)
  const int tid = threadIdx.x;
  const int wv = tid >> 6, l = tid & 63;
  const int wm = wv >> 1, wn = wv & 1;

  // ---- B staging lane addresses (2 gloads: 64 cols x 64B each round) ----
  // col_local(j) = j*64 + wv*16 + (l>>2); slot = l&3 (swizzled at source)
  const char* laneB0;
  const char* laneB1;
  {
    const char* lb[2];
#pragma unroll
    for (int gi = 0; gi < 2; ++gi) {
      int col_local = gi * 64 + wv * 16 + (l >> 2);
      int col = colblk * 128 + col_local;
      int bb = col / NPIX, pix = col - bb * NPIX;
      int prow = (pix / 56 + 1) * PH + (pix % 56 + 1);
      int slot_g = (l & 3) ^ ((col_local >> 1) & 3);
      lb[gi] = (const char*)xT + ((size_t)bb * PPIX + prow) * 512 + slot_g * 16;
    }
    laneB0 = lb[0]; laneB1 = lb[1];
  }
  const char* wtb = (const char*)wt + coh * 8192;
  // tap -> padded-row byte shift
  const int tapsh[9] = {-59 * 512, -58 * 512, -57 * 512, -512, 0, 512, 57 * 512, 58 * 512, 59 * 512};

  // stage K32-stage ST into buffer STG: A 2 gloads + B 2 gloads per thread
#define STAGE(STG, ST) do {                                                 \
    int st_ = (ST); int cs_ = st_ / 9, tap_ = st_ - cs_ * 9;                \
    int sh_ = tapsh[tap_] + cs_ * 64;                                       \
    const char* as_ = wtb + (size_t)st_ * 16384 + wv * 1024 + l * 16;       \
    char* da_ = (STG) + wv * 1024;                                          \
    gload_lds16(as_,        da_);                                           \
    gload_lds16(as_ + 4096, da_ + 4096);                                    \
    char* db_ = (STG) + 8192 + wv * 1024;                                   \
    gload_lds16(laneB0 + sh_, db_);                                         \
    gload_lds16(laneB1 + sh_, db_ + 4096);                                  \
  } while (0)

  // ---- fragment LDS byte offsets (bank-swizzled: slot ^= (row>>1)&3) ----
  int aoff[4], boff[4];
#pragma unroll
  for (int m = 0; m < 4; ++m) {
    int row = wm * 64 + m * 16 + (l & 15);
    aoff[m] = row * 64 + ((((l >> 4) ^ (row >> 1)) & 3) << 4);
  }
#pragma unroll
  for (int n = 0; n < 4; ++n) {
    int row = wn * 64 + n * 16 + (l & 15);
    boff[n] = 8192 + row * 64 + ((((l >> 4) ^ (row >> 1)) & 3) << 4);
  }

  f32x4 acc[4][4];
#pragma unroll
  for (int m = 0; m < 4; ++m)
#pragma unroll
    for (int n = 0; n < 4; ++n) acc[m][n] = (f32x4){0.f, 0.f, 0.f, 0.f};

  // ---- prologue: stage stage-0 into buf0, drain, barrier ----
  STAGE(&lds_[0][0], 0);
  asm volatile("s_waitcnt vmcnt(0)" ::: "memory");
  __builtin_amdgcn_s_barrier();

  for (int s = 0; s < 72; ++s) {
    const char* Ab = &lds_[s & 1][0];
    char* stg = &lds_[(s + 1) & 1][0];
    bf16x8 af[4], bfr[4];
#pragma unroll
    for (int m = 0; m < 4; ++m) af[m] = *(const bf16x8*)(Ab + aoff[m]);
#pragma unroll
    for (int n = 0; n < 4; ++n) bfr[n] = *(const bf16x8*)(Ab + boff[n]);
    if (s < 71) STAGE(stg, s + 1);            // prefetch under this stage's MFMA
    __builtin_amdgcn_s_setprio(1);
#pragma unroll
    for (int m = 0; m < 4; ++m)
#pragma unroll
      for (int n = 0; n < 4; ++n)
        acc[m][n] = __builtin_amdgcn_mfma_f32_16x16x32_bf16(af[m], bfr[n], acc[m][n], 0, 0, 0);
    __builtin_amdgcn_s_setprio(0);
    if (s < 71) {
      asm volatile("s_waitcnt vmcnt(0)" ::: "memory");  // drain covered by sibling blocks
      __builtin_amdgcn_s_barrier();
    }
  }
#undef STAGE

  // ---- epilogue: out = sX*x + sY*conv + sB*conv_b ----
  const int lc = l & 15, lg = l >> 4;
  float sXn[4], sYn[4], sBn[4];
  size_t obase[4];
#pragma unroll
  for (int n = 0; n < 4; ++n) {
    int col = colblk * 128 + wn * 64 + n * 16 + lc;
    int bb = col / NPIX, pix = col - bb * NPIX;
    sXn[n] = scales[bb * 4 + 0];
    sYn[n] = scales[bb * 4 + 1];
    sBn[n] = scales[bb * 4 + 2];
    obase[n] = (size_t)bb * NCH * NPIX + pix;
  }
#pragma unroll
  for (int m = 0; m < 4; ++m) {
#pragma unroll
    for (int j = 0; j < 4; ++j) {
      int co = coh * 128 + wm * 64 + m * 16 + lg * 4 + j;
      float cbv = conv_b[co];
      size_t cooff = (size_t)co * NPIX;
#pragma unroll
      for (int n = 0; n < 4; ++n) {
        size_t idx = obase[n] + cooff;
        out[idx] = sXn[n] * x[idx] + sYn[n] * acc[m][n][j] + sBn[n] * cbv;
      }
    }
  }
}

extern "C" void kernel_launch(void* const* d_in, const int* in_sizes, int n_in,
                              void* d_out, int out_size, void* d_ws, size_t ws_size,
                              hipStream_t stream) {
  const float* x      = (const float*)d_in[0];
  const float* phi_w  = (const float*)d_in[1];
  const float* phi_b  = (const float*)d_in[2];
  const float* rms_w  = (const float*)d_in[3];
  const float* a_pre  = (const float*)d_in[4];
  const float* a_post = (const float*)d_in[5];
  const float* a_res  = (const float*)d_in[6];
  const float* conv_w = (const float*)d_in[7];
  const float* conv_b = (const float*)d_in[8];
  float* out = (float*)d_out;

  char* ws = (char*)d_ws;
  unsigned short* xT = (unsigned short*)ws;
  const size_t XT_BYTES = (size_t)NB * PPIX * NCH * 2;            // 55,115,776
  float* pp2 = (float*)(ws + XT_BYTES);
  const size_t PP_BYTES = (size_t)NB * 49 * 256 * 4;              // 1,605,632
  float* scales = (float*)(ws + XT_BYTES + PP_BYTES);
  unsigned short* wt = (unsigned short*)(ws + XT_BYTES + PP_BYTES + 512);

  prep_k<<<dim3(144 + 3648), dim3(256), 0, stream>>>(conv_w, wt, xT);
  transpose_x<<<dim3(49, 4, NB), dim3(256), 0, stream>>>(x, xT, pp2);
  head_k<<<dim3(NB), dim3(256), 0, stream>>>(pp2, phi_w, phi_b, rms_w, a_pre, a_post, a_res, scales);
  conv_k<<<dim3(784, 2), dim3(256), 0, stream>>>(xT, wt, x, conv_b, scales, out);
}

// Round 12
// 191.041 us; speedup vs baseline: 1.0739x; 1.0544x over previous
//
#include <hip/hip_runtime.h>
#include <stdint.h>

// Problem constants
#define NB   32
#define NCH  256
#define NPIX 3136      // 56*56
#define PH   58        // padded width/height (56+2)
#define PPIX 3364      // 58*58
#define NCOL 100352    // NB*NPIX

typedef __bf16 bf16x8 __attribute__((ext_vector_type(8)));
typedef float  f32x4  __attribute__((ext_vector_type(4)));

__device__ __forceinline__ unsigned short f2bf(float f) {
  unsigned int u = __float_as_uint(f);
  u += 0x7fff + ((u >> 16) & 1);           // RNE
  return (unsigned short)(u >> 16);
}
__device__ __forceinline__ float bf2f(unsigned int us) {
  return __uint_as_float(us << 16);
}

// async global->LDS, 16B per lane. LDS ptr must be wave-uniform; HW adds lane*16.
__device__ __forceinline__ void gload_lds16(const void* g, void* l) {
  __builtin_amdgcn_global_load_lds(
      (const __attribute__((address_space(1))) unsigned int*)(uintptr_t)g,
      (__attribute__((address_space(3))) unsigned int*)(unsigned int)(uintptr_t)l,
      16, 0, 0);
}

// ---------------- prep: weight tiles + zero xT borders (fused, independent work) ----------------
// wt layout: [stage=cs*9+tap][co 256][slot 4][e 8] bf16, with bank-swizzle baked in:
// LDS slot s holds global ci-slot (s ^ (((co&127)>>1)&3)).
__global__ __launch_bounds__(256) void prep_k(const float* __restrict__ cw,
                                              unsigned short* __restrict__ wt,
                                              unsigned short* __restrict__ xT) {
  int blk = blockIdx.x;
  int tid = threadIdx.x;
  if (blk < 144) {
    int stage = blk >> 1, half = blk & 1;
    int tap = stage % 9, cs = stage / 9;
    unsigned short* dst = wt + (size_t)stage * 8192 + half * 4096;
#pragma unroll
    for (int e8 = 0; e8 < 16; ++e8) {
      int j = e8 * 256 + tid;           // 0..4095 over [128co][32ci]
      int ci_l = j & 31, co_l = j >> 5;
      int slot = ci_l >> 3, e = ci_l & 7;
      int slot_g = slot ^ ((co_l >> 1) & 3);        // inverse swizzle at source
      int co = half * 128 + co_l, ci = cs * 32 + slot_g * 8 + e;
      dst[j] = f2bf(cw[((size_t)co * 256 + ci) * 9 + tap]);
    }
  } else {
    int g = (blk - 144) * 256 + tid;    // uint index, < 933888
    int b = g / 29184;                   // 228 border rows * 128 uints
    int rem = g - b * 29184;
    int ridx = rem >> 7, ui = rem & 127;
    int row;
    if (ridx < 58)       row = ridx;
    else if (ridx < 116) row = 57 * 58 + (ridx - 58);
    else { int r2 = ridx - 116; row = (1 + (r2 >> 1)) * 58 + ((r2 & 1) ? 57 : 0); }
    ((unsigned int*)(xT + ((size_t)b * PPIX + row) * NCH))[ui] = 0;
  }
}

// ---------------- transpose x [b][ci][pix] fp32 -> xT [b][padpix][ci] bf16, + partial pooling ----------------
__global__ __launch_bounds__(256) void transpose_x(const float* __restrict__ x,
                                                   unsigned short* __restrict__ xT,
                                                   float* __restrict__ pp2) {
  int pblk = blockIdx.x, ciblk = blockIdx.y, b = blockIdx.z;
  int p0 = pblk * 64, ci0 = ciblk * 64;
  __shared__ unsigned short t[64][65];
  int tid = threadIdx.x;
  int pq = tid & 15, cq = tid >> 4;
  const float* xb = x + ((size_t)b * NCH + ci0) * NPIX + p0;
#pragma unroll
  for (int pass = 0; pass < 4; ++pass) {
    int ci_l = pass * 16 + cq;
    float4 v = *(const float4*)&xb[(size_t)ci_l * NPIX + pq * 4];
    t[ci_l][pq * 4 + 0] = f2bf(v.x);
    t[ci_l][pq * 4 + 1] = f2bf(v.y);
    t[ci_l][pq * 4 + 2] = f2bf(v.z);
    t[ci_l][pq * 4 + 3] = f2bf(v.w);
  }
  __syncthreads();
  if (tid < 64) {
    float s = 0;
#pragma unroll
    for (int p = 0; p < 64; ++p) s += bf2f(t[tid][p]);
    pp2[((size_t)b * 49 + pblk) * 256 + ci0 + tid] = s;
  }
  int cio = (tid & 31) * 2, jo = tid >> 5;
#pragma unroll
  for (int pass = 0; pass < 8; ++pass) {
    int jj = pass * 8 + jo;
    int p = p0 + jj;
    int h = p / 56, w = p % 56;
    int row = (h + 1) * PH + (w + 1);
    unsigned int v = (unsigned int)t[cio][jj] | ((unsigned int)t[cio + 1][jj] << 16);
    *(unsigned int*)(xT + ((size_t)b * PPIX + row) * NCH + ci0 + cio) = v;
  }
}

// ---------------- head: rmsnorm + phi + sigmoids + sinkhorn -> 3 scalars per batch ----------------
__global__ __launch_bounds__(256) void head_k(const float* __restrict__ pp2,
    const float* __restrict__ phi_w, const float* __restrict__ phi_b,
    const float* __restrict__ rms_w, const float* __restrict__ a_pre,
    const float* __restrict__ a_post, const float* __restrict__ a_res,
    float* __restrict__ scales) {
  int b = blockIdx.x;
  int t = threadIdx.x;
  __shared__ float red[4];
  __shared__ float coeff[24];
  float s = 0;
  for (int ch = 0; ch < 49; ++ch) s += pp2[((size_t)b * 49 + ch) * 256 + t];
  float pooled = s * (1.0f / (float)NPIX);
  float v = pooled * pooled;
#pragma unroll
  for (int off = 32; off; off >>= 1) v += __shfl_down(v, off);
  if ((t & 63) == 0) red[t >> 6] = v;
  __syncthreads();
  float ms = (red[0] + red[1] + red[2] + red[3]) * (1.0f / 256.0f);
  float inv = rsqrtf(ms + 1e-20f);
  __syncthreads();
  for (int o = 0; o < 24; ++o) {
    float ws_ = 0;
#pragma unroll
    for (int i = 0; i < 4; ++i) ws_ += phi_w[(size_t)o * 1024 + i * 256 + t] * rms_w[i * 256 + t];
    float c = pooled * ws_;
#pragma unroll
    for (int off = 32; off; off >>= 1) c += __shfl_down(c, off);
    if ((t & 63) == 0) red[t >> 6] = c;
    __syncthreads();
    if (t == 0) coeff[o] = inv * (red[0] + red[1] + red[2] + red[3]) + phi_b[o];
    __syncthreads();
  }
  if (t == 0) {
    float ap = a_pre[0], apo = a_post[0], ar = a_res[0];
    float spre = 0, psum = 0;
#pragma unroll
    for (int i = 0; i < 4; ++i) {
      spre += 1.0f / (1.0f + expf(-ap * coeff[i]));
      psum += 2.0f / (1.0f + expf(-apo * coeff[4 + i]));
    }
    float M[4][4];
#pragma unroll
    for (int i = 0; i < 4; ++i)
#pragma unroll
      for (int j = 0; j < 4; ++j) M[i][j] = expf(ar * coeff[8 + i * 4 + j]);
    for (int it = 0; it < 20; ++it) {
#pragma unroll
      for (int i = 0; i < 4; ++i) {
        float rs = M[i][0] + M[i][1] + M[i][2] + M[i][3];
        float rr = 1.0f / rs;
        M[i][0] *= rr; M[i][1] *= rr; M[i][2] *= rr; M[i][3] *= rr;
      }
#pragma unroll
      for (int j = 0; j < 4; ++j) {
        float cs2 = M[0][j] + M[1][j] + M[2][j] + M[3][j];
        float rr = 1.0f / cs2;
        M[0][j] *= rr; M[1][j] *= rr; M[2][j] *= rr; M[3][j] *= rr;
      }
    }
    float r = 0.25f * (M[0][0] + M[1][1] + M[2][2] + M[3][3]);
    float pm = 0.25f * psum;
    scales[b * 4 + 0] = r;          // on x
    scales[b * 4 + 1] = pm * spre;  // on conv(x)
    scales[b * 4 + 2] = pm;         // on conv_b
  }
}

// ---------------- conv implicit GEMM: high-residency 128x128 config, notch 2.
// 128co x 128col tile, 256 thr / 4 waves (2M x 2N), acc 64 + arch 64 = 128 regs/thread
// -> launch_bounds(256,4): 4 waves/SIMD = 4 co-resident blocks/CU (16 waves/CU).
// Grid flattened to 1568 with XCD chunk swizzle (1568 = 8 x 196): each XCD gets a
// contiguous work chunk; co-half pairs of one colblk are adjacent -> B-tile L2 reuse.
// Simple 2-phase dbuf K-loop; inter-block wave overlap supplies pipelining (R11: +9%).
// XOR bank swizzle (0 conflicts). ----------------
__global__ __launch_bounds__(256, 4) void conv_k(
    const unsigned short* __restrict__ xT, const unsigned short* __restrict__ wt,
    const float* __restrict__ x, const float* __restrict__ conv_b,
    const float* __restrict__ scales, float* __restrict__ out) {
  // per buffer: [A 8 KB: 128co x 32ci][B 8 KB: 128col x 32ci]
  __shared__ __align__(16) char lds_[2][16384];
  // XCD chunk swizzle: hw bid -> work id so each XCD owns contiguous work
  const int wgid = (blockIdx.x & 7) * 196 + (blockIdx.x >> 3);
  const int colblk = wgid >> 1;       // 784
  const int coh = wgid & 1;           // co half
  const int tid = threadIdx.x;
  const int wv = tid >> 6, l = tid & 63;
  const int wm = wv >> 1, wn = wv & 1;

  // ---- B staging lane addresses (2 gloads: 64 cols x 64B each round) ----
  const char* laneB0;
  const char* laneB1;
  {
    const char* lb[2];
#pragma unroll
    for (int gi = 0; gi < 2; ++gi) {
      int col_local = gi * 64 + wv * 16 + (l >> 2);
      int col = colblk * 128 + col_local;
      int bb = col / NPIX, pix = col - bb * NPIX;
      int prow = (pix / 56 + 1) * PH + (pix % 56 + 1);
      int slot_g = (l & 3) ^ ((col_local >> 1) & 3);
      lb[gi] = (const char*)xT + ((size_t)bb * PPIX + prow) * 512 + slot_g * 16;
    }
    laneB0 = lb[0]; laneB1 = lb[1];
  }
  const char* wtb = (const char*)wt + coh * 8192;
  // tap -> padded-row byte shift
  const int tapsh[9] = {-59 * 512, -58 * 512, -57 * 512, -512, 0, 512, 57 * 512, 58 * 512, 59 * 512};

  // stage K32-stage ST into buffer STG: A 2 gloads + B 2 gloads per thread
#define STAGE(STG, ST) do {                                                 \
    int st_ = (ST); int cs_ = st_ / 9, tap_ = st_ - cs_ * 9;                \
    int sh_ = tapsh[tap_] + cs_ * 64;                                       \
    const char* as_ = wtb + (size_t)st_ * 16384 + wv * 1024 + l * 16;       \
    char* da_ = (STG) + wv * 1024;                                          \
    gload_lds16(as_,        da_);                                           \
    gload_lds16(as_ + 4096, da_ + 4096);                                    \
    char* db_ = (STG) + 8192 + wv * 1024;                                   \
    gload_lds16(laneB0 + sh_, db_);                                         \
    gload_lds16(laneB1 + sh_, db_ + 4096);                                  \
  } while (0)

  // ---- fragment LDS byte offsets (bank-swizzled: slot ^= (row>>1)&3) ----
  int aoff[4], boff[4];
#pragma unroll
  for (int m = 0; m < 4; ++m) {
    int row = wm * 64 + m * 16 + (l & 15);
    aoff[m] = row * 64 + ((((l >> 4) ^ (row >> 1)) & 3) << 4);
  }
#pragma unroll
  for (int n = 0; n < 4; ++n) {
    int row = wn * 64 + n * 16 + (l & 15);
    boff[n] = 8192 + row * 64 + ((((l >> 4) ^ (row >> 1)) & 3) << 4);
  }

  f32x4 acc[4][4];
#pragma unroll
  for (int m = 0; m < 4; ++m)
#pragma unroll
    for (int n = 0; n < 4; ++n) acc[m][n] = (f32x4){0.f, 0.f, 0.f, 0.f};

  // ---- prologue: stage stage-0 into buf0, drain, barrier ----
  STAGE(&lds_[0][0], 0);
  asm volatile("s_waitcnt vmcnt(0)" ::: "memory");
  __builtin_amdgcn_s_barrier();

  for (int s = 0; s < 72; ++s) {
    const char* Ab = &lds_[s & 1][0];
    char* stg = &lds_[(s + 1) & 1][0];
    bf16x8 af[4], bfr[4];
#pragma unroll
    for (int m = 0; m < 4; ++m) af[m] = *(const bf16x8*)(Ab + aoff[m]);
#pragma unroll
    for (int n = 0; n < 4; ++n) bfr[n] = *(const bf16x8*)(Ab + boff[n]);
    if (s < 71) STAGE(stg, s + 1);            // prefetch under this stage's MFMA
    __builtin_amdgcn_s_setprio(1);
#pragma unroll
    for (int m = 0; m < 4; ++m)
#pragma unroll
      for (int n = 0; n < 4; ++n)
        acc[m][n] = __builtin_amdgcn_mfma_f32_16x16x32_bf16(af[m], bfr[n], acc[m][n], 0, 0, 0);
    __builtin_amdgcn_s_setprio(0);
    if (s < 71) {
      asm volatile("s_waitcnt vmcnt(0)" ::: "memory");  // drain covered by sibling blocks
      __builtin_amdgcn_s_barrier();
    }
  }
#undef STAGE

  // ---- epilogue: out = sX*x + sY*conv + sB*conv_b ----
  const int lc = l & 15, lg = l >> 4;
  float sXn[4], sYn[4], sBn[4];
  size_t obase[4];
#pragma unroll
  for (int n = 0; n < 4; ++n) {
    int col = colblk * 128 + wn * 64 + n * 16 + lc;
    int bb = col / NPIX, pix = col - bb * NPIX;
    sXn[n] = scales[bb * 4 + 0];
    sYn[n] = scales[bb * 4 + 1];
    sBn[n] = scales[bb * 4 + 2];
    obase[n] = (size_t)bb * NCH * NPIX + pix;
  }
#pragma unroll
  for (int m = 0; m < 4; ++m) {
#pragma unroll
    for (int j = 0; j < 4; ++j) {
      int co = coh * 128 + wm * 64 + m * 16 + lg * 4 + j;
      float cbv = conv_b[co];
      size_t cooff = (size_t)co * NPIX;
#pragma unroll
      for (int n = 0; n < 4; ++n) {
        size_t idx = obase[n] + cooff;
        out[idx] = sXn[n] * x[idx] + sYn[n] * acc[m][n][j] + sBn[n] * cbv;
      }
    }
  }
}

extern "C" void kernel_launch(void* const* d_in, const int* in_sizes, int n_in,
                              void* d_out, int out_size, void* d_ws, size_t ws_size,
                              hipStream_t stream) {
  const float* x      = (const float*)d_in[0];
  const float* phi_w  = (const float*)d_in[1];
  const float* phi_b  = (const float*)d_in[2];
  const float* rms_w  = (const float*)d_in[3];
  const float* a_pre  = (const float*)d_in[4];
  const float* a_post = (const float*)d_in[5];
  const float* a_res  = (const float*)d_in[6];
  const float* conv_w = (const float*)d_in[7];
  const float* conv_b = (const float*)d_in[8];
  float* out = (float*)d_out;

  char* ws = (char*)d_ws;
  unsigned short* xT = (unsigned short*)ws;
  const size_t XT_BYTES = (size_t)NB * PPIX * NCH * 2;            // 55,115,776
  float* pp2 = (float*)(ws + XT_BYTES);
  const size_t PP_BYTES = (size_t)NB * 49 * 256 * 4;              // 1,605,632
  float* scales = (float*)(ws + XT_BYTES + PP_BYTES);
  unsigned short* wt = (unsigned short*)(ws + XT_BYTES + PP_BYTES + 512);

  prep_k<<<dim3(144 + 3648), dim3(256), 0, stream>>>(conv_w, wt, xT);
  transpose_x<<<dim3(49, 4, NB), dim3(256), 0, stream>>>(x, xT, pp2);
  head_k<<<dim3(NB), dim3(256), 0, stream>>>(pp2, phi_w, phi_b, rms_w, a_pre, a_post, a_res, scales);
  conv_k<<<dim3(1568), dim3(256), 0, stream>>>(xT, wt, x, conv_b, scales, out);
}

// Round 14
// 189.357 us; speedup vs baseline: 1.0834x; 1.0089x over previous
//
#include <hip/hip_runtime.h>
#include <stdint.h>

// Problem constants
#define NB   32
#define NCH  256
#define NPIX 3136      // 56*56
#define PH   58        // padded width/height (56+2)
#define PPIX 3364      // 58*58
#define NCOL 100352    // NB*NPIX

typedef __bf16 bf16x8 __attribute__((ext_vector_type(8)));
typedef float  f32x4  __attribute__((ext_vector_type(4)));

__device__ __forceinline__ unsigned short f2bf(float f) {
  unsigned int u = __float_as_uint(f);
  u += 0x7fff + ((u >> 16) & 1);           // RNE
  return (unsigned short)(u >> 16);
}
__device__ __forceinline__ float bf2f(unsigned int us) {
  return __uint_as_float(us << 16);
}

// async global->LDS, 16B per lane. LDS ptr must be wave-uniform; HW adds lane*16.
__device__ __forceinline__ void gload_lds16(const void* g, void* l) {
  __builtin_amdgcn_global_load_lds(
      (const __attribute__((address_space(1))) unsigned int*)(uintptr_t)g,
      (__attribute__((address_space(3))) unsigned int*)(unsigned int)(uintptr_t)l,
      16, 0, 0);
}

// ---------------- fused pre-pass: transpose+pool (blocks 0..6271), weight tiles
// (6272..6415), xT border zero (6416..10063). All sub-bodies verbatim from the
// R12-verified kernels; whole-block demux only. ----------------
// wt layout: [stage=cs*9+tap][co 256][slot 4][e 8] bf16, bank-swizzle baked in:
// LDS slot s holds global ci-slot (s ^ (((co&127)>>1)&3)).
__global__ __launch_bounds__(256) void pre_k(const float* __restrict__ x,
                                             const float* __restrict__ cw,
                                             unsigned short* __restrict__ wt,
                                             unsigned short* __restrict__ xT,
                                             float* __restrict__ pp2) {
  __shared__ unsigned short t[64][65];
  int blk = blockIdx.x;
  int tid = threadIdx.x;
  if (blk < 6272) {
    // ---- transpose x [b][ci][pix] fp32 -> xT [b][padpix][ci] bf16, + partial pooling ----
    int pblk = blk % 49, rest = blk / 49;
    int ciblk = rest & 3, b = rest >> 2;
    int p0 = pblk * 64, ci0 = ciblk * 64;
    int pq = tid & 15, cq = tid >> 4;
    const float* xb = x + ((size_t)b * NCH + ci0) * NPIX + p0;
#pragma unroll
    for (int pass = 0; pass < 4; ++pass) {
      int ci_l = pass * 16 + cq;
      float4 v = *(const float4*)&xb[(size_t)ci_l * NPIX + pq * 4];
      t[ci_l][pq * 4 + 0] = f2bf(v.x);
      t[ci_l][pq * 4 + 1] = f2bf(v.y);
      t[ci_l][pq * 4 + 2] = f2bf(v.z);
      t[ci_l][pq * 4 + 3] = f2bf(v.w);
    }
    __syncthreads();
    if (tid < 64) {
      float s = 0;
#pragma unroll
      for (int p = 0; p < 64; ++p) s += bf2f(t[tid][p]);
      pp2[((size_t)b * 49 + pblk) * 256 + ci0 + tid] = s;
    }
    int cio = (tid & 31) * 2, jo = tid >> 5;
#pragma unroll
    for (int pass = 0; pass < 8; ++pass) {
      int jj = pass * 8 + jo;
      int p = p0 + jj;
      int h = p / 56, w = p % 56;
      int row = (h + 1) * PH + (w + 1);
      unsigned int v = (unsigned int)t[cio][jj] | ((unsigned int)t[cio + 1][jj] << 16);
      *(unsigned int*)(xT + ((size_t)b * PPIX + row) * NCH + ci0 + cio) = v;
    }
  } else if (blk < 6272 + 144) {
    // ---- weight tiles ----
    int wblk = blk - 6272;
    int stage = wblk >> 1, half = wblk & 1;
    int tap = stage % 9, cs = stage / 9;
    unsigned short* dst = wt + (size_t)stage * 8192 + half * 4096;
#pragma unroll
    for (int e8 = 0; e8 < 16; ++e8) {
      int j = e8 * 256 + tid;           // 0..4095 over [128co][32ci]
      int ci_l = j & 31, co_l = j >> 5;
      int slot = ci_l >> 3, e = ci_l & 7;
      int slot_g = slot ^ ((co_l >> 1) & 3);        // inverse swizzle at source
      int co = half * 128 + co_l, ci = cs * 32 + slot_g * 8 + e;
      dst[j] = f2bf(cw[((size_t)co * 256 + ci) * 9 + tap]);
    }
  } else {
    // ---- zero xT borders ----
    int g = (blk - 6416) * 256 + tid;    // uint index, < 933888
    int b = g / 29184;                   // 228 border rows * 128 uints
    int rem = g - b * 29184;
    int ridx = rem >> 7, ui = rem & 127;
    int row;
    if (ridx < 58)       row = ridx;
    else if (ridx < 116) row = 57 * 58 + (ridx - 58);
    else { int r2 = ridx - 116; row = (1 + (r2 >> 1)) * 58 + ((r2 & 1) ? 57 : 0); }
    ((unsigned int*)(xT + ((size_t)b * PPIX + row) * NCH))[ui] = 0;
  }
}

// ---------------- head: rmsnorm + phi + sigmoids + sinkhorn -> 3 scalars per batch ----------------
__global__ __launch_bounds__(256) void head_k(const float* __restrict__ pp2,
    const float* __restrict__ phi_w, const float* __restrict__ phi_b,
    const float* __restrict__ rms_w, const float* __restrict__ a_pre,
    const float* __restrict__ a_post, const float* __restrict__ a_res,
    float* __restrict__ scales) {
  int b = blockIdx.x;
  int t = threadIdx.x;
  __shared__ float red[4];
  __shared__ float coeff[24];
  float s = 0;
  for (int ch = 0; ch < 49; ++ch) s += pp2[((size_t)b * 49 + ch) * 256 + t];
  float pooled = s * (1.0f / (float)NPIX);
  float v = pooled * pooled;
#pragma unroll
  for (int off = 32; off; off >>= 1) v += __shfl_down(v, off);
  if ((t & 63) == 0) red[t >> 6] = v;
  __syncthreads();
  float ms = (red[0] + red[1] + red[2] + red[3]) * (1.0f / 256.0f);
  float inv = rsqrtf(ms + 1e-20f);
  __syncthreads();
  for (int o = 0; o < 24; ++o) {
    float ws_ = 0;
#pragma unroll
    for (int i = 0; i < 4; ++i) ws_ += phi_w[(size_t)o * 1024 + i * 256 + t] * rms_w[i * 256 + t];
    float c = pooled * ws_;
#pragma unroll
    for (int off = 32; off; off >>= 1) c += __shfl_down(c, off);
    if ((t & 63) == 0) red[t >> 6] = c;
    __syncthreads();
    if (t == 0) coeff[o] = inv * (red[0] + red[1] + red[2] + red[3]) + phi_b[o];
    __syncthreads();
  }
  if (t == 0) {
    float ap = a_pre[0], apo = a_post[0], ar = a_res[0];
    float spre = 0, psum = 0;
#pragma unroll
    for (int i = 0; i < 4; ++i) {
      spre += 1.0f / (1.0f + expf(-ap * coeff[i]));
      psum += 2.0f / (1.0f + expf(-apo * coeff[4 + i]));
    }
    float M[4][4];
#pragma unroll
    for (int i = 0; i < 4; ++i)
#pragma unroll
      for (int j = 0; j < 4; ++j) M[i][j] = expf(ar * coeff[8 + i * 4 + j]);
    for (int it = 0; it < 20; ++it) {
#pragma unroll
      for (int i = 0; i < 4; ++i) {
        float rs = M[i][0] + M[i][1] + M[i][2] + M[i][3];
        float rr = 1.0f / rs;
        M[i][0] *= rr; M[i][1] *= rr; M[i][2] *= rr; M[i][3] *= rr;
      }
#pragma unroll
      for (int j = 0; j < 4; ++j) {
        float cs2 = M[0][j] + M[1][j] + M[2][j] + M[3][j];
        float rr = 1.0f / cs2;
        M[0][j] *= rr; M[1][j] *= rr; M[2][j] *= rr; M[3][j] *= rr;
      }
    }
    float r = 0.25f * (M[0][0] + M[1][1] + M[2][2] + M[3][3]);
    float pm = 0.25f * psum;
    scales[b * 4 + 0] = r;          // on x
    scales[b * 4 + 1] = pm * spre;  // on conv(x)
    scales[b * 4 + 2] = pm;         // on conv_b
  }
}

// ---------------- conv implicit GEMM: R12 kernel VERBATIM (post-timing verified).
// 128co x 128col tile, 256 thr / 4 waves (2M x 2N), acc 64 + arch 64 = 128 regs/thread
// -> launch_bounds(256,4): 4 waves/SIMD = 4 co-resident blocks/CU (16 waves/CU).
// Grid 1568 with XCD chunk swizzle; co-half pairs adjacent -> B-tile L2 reuse.
// Simple 2-phase dbuf K-loop; inter-block wave overlap supplies pipelining (R11/R12: +15%).
// XOR bank swizzle (0 conflicts). ----------------
__global__ __launch_bounds__(256, 4) void conv_k(
    const unsigned short* __restrict__ xT, const unsigned short* __restrict__ wt,
    const float* __restrict__ x, const float* __restrict__ conv_b,
    const float* __restrict__ scales, float* __restrict__ out) {
  // per buffer: [A 8 KB: 128co x 32ci][B 8 KB: 128col x 32ci]
  __shared__ __align__(16) char lds_[2][16384];
  // XCD chunk swizzle: hw bid -> work id so each XCD owns contiguous work
  const int wgid = (blockIdx.x & 7) * 196 + (blockIdx.x >> 3);
  const int colblk = wgid >> 1;       // 784
  const int coh = wgid & 1;           // co half
  const int tid = threadIdx.x;
  const int wv = tid >> 6, l = tid & 63;
  const int wm = wv >> 1, wn = wv & 1;

  // ---- B staging lane addresses (2 gloads: 64 cols x 64B each round) ----
  const char* laneB0;
  const char* laneB1;
  {
    const char* lb[2];
#pragma unroll
    for (int gi = 0; gi < 2; ++gi) {
      int col_local = gi * 64 + wv * 16 + (l >> 2);
      int col = colblk * 128 + col_local;
      int bb = col / NPIX, pix = col - bb * NPIX;
      int prow = (pix / 56 + 1) * PH + (pix % 56 + 1);
      int slot_g = (l & 3) ^ ((col_local >> 1) & 3);
      lb[gi] = (const char*)xT + ((size_t)bb * PPIX + prow) * 512 + slot_g * 16;
    }
    laneB0 = lb[0]; laneB1 = lb[1];
  }
  const char* wtb = (const char*)wt + coh * 8192;
  // tap -> padded-row byte shift
  const int tapsh[9] = {-59 * 512, -58 * 512, -57 * 512, -512, 0, 512, 57 * 512, 58 * 512, 59 * 512};

  // stage K32-stage ST into buffer STG: A 2 gloads + B 2 gloads per thread
#define STAGE(STG, ST) do {                                                 \
    int st_ = (ST); int cs_ = st_ / 9, tap_ = st_ - cs_ * 9;                \
    int sh_ = tapsh[tap_] + cs_ * 64;                                       \
    const char* as_ = wtb + (size_t)st_ * 16384 + wv * 1024 + l * 16;       \
    char* da_ = (STG) + wv * 1024;                                          \
    gload_lds16(as_,        da_);                                           \
    gload_lds16(as_ + 4096, da_ + 4096);                                    \
    char* db_ = (STG) + 8192 + wv * 1024;                                   \
    gload_lds16(laneB0 + sh_, db_);                                         \
    gload_lds16(laneB1 + sh_, db_ + 4096);                                  \
  } while (0)

  // ---- fragment LDS byte offsets (bank-swizzled: slot ^= (row>>1)&3) ----
  int aoff[4], boff[4];
#pragma unroll
  for (int m = 0; m < 4; ++m) {
    int row = wm * 64 + m * 16 + (l & 15);
    aoff[m] = row * 64 + ((((l >> 4) ^ (row >> 1)) & 3) << 4);
  }
#pragma unroll
  for (int n = 0; n < 4; ++n) {
    int row = wn * 64 + n * 16 + (l & 15);
    boff[n] = 8192 + row * 64 + ((((l >> 4) ^ (row >> 1)) & 3) << 4);
  }

  f32x4 acc[4][4];
#pragma unroll
  for (int m = 0; m < 4; ++m)
#pragma unroll
    for (int n = 0; n < 4; ++n) acc[m][n] = (f32x4){0.f, 0.f, 0.f, 0.f};

  // ---- prologue: stage stage-0 into buf0, drain, barrier ----
  STAGE(&lds_[0][0], 0);
  asm volatile("s_waitcnt vmcnt(0)" ::: "memory");
  __builtin_amdgcn_s_barrier();

  for (int s = 0; s < 72; ++s) {
    const char* Ab = &lds_[s & 1][0];
    char* stg = &lds_[(s + 1) & 1][0];
    bf16x8 af[4], bfr[4];
#pragma unroll
    for (int m = 0; m < 4; ++m) af[m] = *(const bf16x8*)(Ab + aoff[m]);
#pragma unroll
    for (int n = 0; n < 4; ++n) bfr[n] = *(const bf16x8*)(Ab + boff[n]);
    if (s < 71) STAGE(stg, s + 1);            // prefetch under this stage's MFMA
    __builtin_amdgcn_s_setprio(1);
#pragma unroll
    for (int m = 0; m < 4; ++m)
#pragma unroll
      for (int n = 0; n < 4; ++n)
        acc[m][n] = __builtin_amdgcn_mfma_f32_16x16x32_bf16(af[m], bfr[n], acc[m][n], 0, 0, 0);
    __builtin_amdgcn_s_setprio(0);
    if (s < 71) {
      asm volatile("s_waitcnt vmcnt(0)" ::: "memory");  // drain covered by sibling blocks
      __builtin_amdgcn_s_barrier();
    }
  }
#undef STAGE

  // ---- epilogue: out = sX*x + sY*conv + sB*conv_b ----
  const int lc = l & 15, lg = l >> 4;
  float sXn[4], sYn[4], sBn[4];
  size_t obase[4];
#pragma unroll
  for (int n = 0; n < 4; ++n) {
    int col = colblk * 128 + wn * 64 + n * 16 + lc;
    int bb = col / NPIX, pix = col - bb * NPIX;
    sXn[n] = scales[bb * 4 + 0];
    sYn[n] = scales[bb * 4 + 1];
    sBn[n] = scales[bb * 4 + 2];
    obase[n] = (size_t)bb * NCH * NPIX + pix;
  }
#pragma unroll
  for (int m = 0; m < 4; ++m) {
#pragma unroll
    for (int j = 0; j < 4; ++j) {
      int co = coh * 128 + wm * 64 + m * 16 + lg * 4 + j;
      float cbv = conv_b[co];
      size_t cooff = (size_t)co * NPIX;
#pragma unroll
      for (int n = 0; n < 4; ++n) {
        size_t idx = obase[n] + cooff;
        out[idx] = sXn[n] * x[idx] + sYn[n] * acc[m][n][j] + sBn[n] * cbv;
      }
    }
  }
}

extern "C" void kernel_launch(void* const* d_in, const int* in_sizes, int n_in,
                              void* d_out, int out_size, void* d_ws, size_t ws_size,
                              hipStream_t stream) {
  const float* x      = (const float*)d_in[0];
  const float* phi_w  = (const float*)d_in[1];
  const float* phi_b  = (const float*)d_in[2];
  const float* rms_w  = (const float*)d_in[3];
  const float* a_pre  = (const float*)d_in[4];
  const float* a_post = (const float*)d_in[5];
  const float* a_res  = (const float*)d_in[6];
  const float* conv_w = (const float*)d_in[7];
  const float* conv_b = (const float*)d_in[8];
  float* out = (float*)d_out;

  char* ws = (char*)d_ws;
  unsigned short* xT = (unsigned short*)ws;
  const size_t XT_BYTES = (size_t)NB * PPIX * NCH * 2;            // 55,115,776
  float* pp2 = (float*)(ws + XT_BYTES);
  const size_t PP_BYTES = (size_t)NB * 49 * 256 * 4;              // 1,605,632
  float* scales = (float*)(ws + XT_BYTES + PP_BYTES);
  unsigned short* wt = (unsigned short*)(ws + XT_BYTES + PP_BYTES + 512);

  pre_k<<<dim3(6272 + 144 + 3648), dim3(256), 0, stream>>>(x, conv_w, wt, xT, pp2);
  head_k<<<dim3(NB), dim3(256), 0, stream>>>(pp2, phi_w, phi_b, rms_w, a_pre, a_post, a_res, scales);
  conv_k<<<dim3(1568), dim3(256), 0, stream>>>(xT, wt, x, conv_b, scales, out);
}

// Round 15
// 187.374 us; speedup vs baseline: 1.0949x; 1.0106x over previous
//
#include <hip/hip_runtime.h>
#include <stdint.h>

// Problem constants
#define NB   32
#define NCH  256
#define NPIX 3136      // 56*56
#define PH   58        // padded width/height (56+2)
#define PPIX 3364      // 58*58
#define NCOL 100352    // NB*NPIX

typedef __bf16 bf16x8 __attribute__((ext_vector_type(8)));
typedef float  f32x4  __attribute__((ext_vector_type(4)));

__device__ __forceinline__ unsigned short f2bf(float f) {
  unsigned int u = __float_as_uint(f);
  u += 0x7fff + ((u >> 16) & 1);           // RNE
  return (unsigned short)(u >> 16);
}
__device__ __forceinline__ float bf2f(unsigned int us) {
  return __uint_as_float(us << 16);
}

// async global->LDS, 16B per lane. LDS ptr must be wave-uniform; HW adds lane*16.
__device__ __forceinline__ void gload_lds16(const void* g, void* l) {
  __builtin_amdgcn_global_load_lds(
      (const __attribute__((address_space(1))) unsigned int*)(uintptr_t)g,
      (__attribute__((address_space(3))) unsigned int*)(unsigned int)(uintptr_t)l,
      16, 0, 0);
}

// ---------------- fused pre-pass: transpose+pool (blocks 0..6271), weight tiles
// (6272..6415), xT border zero (6416..10063).
// R15 change: pooling folded into the load phase — per-thread fp32 partial + 16-lane
// shfl_xor reduce (all 256 threads busy; removes the 64-thread serial loop). ----------------
// wt layout: [stage=cs*9+tap][co 256][slot 4][e 8] bf16, bank-swizzle baked in:
// LDS slot s holds global ci-slot (s ^ (((co&127)>>1)&3)).
__global__ __launch_bounds__(256) void pre_k(const float* __restrict__ x,
                                             const float* __restrict__ cw,
                                             unsigned short* __restrict__ wt,
                                             unsigned short* __restrict__ xT,
                                             float* __restrict__ pp2) {
  __shared__ unsigned short t[64][65];
  int blk = blockIdx.x;
  int tid = threadIdx.x;
  if (blk < 6272) {
    // ---- transpose x [b][ci][pix] fp32 -> xT [b][padpix][ci] bf16, + fused pooling ----
    int pblk = blk % 49, rest = blk / 49;
    int ciblk = rest & 3, b = rest >> 2;
    int p0 = pblk * 64, ci0 = ciblk * 64;
    int pq = tid & 15, cq = tid >> 4;
    const float* xb = x + ((size_t)b * NCH + ci0) * NPIX + p0;
    float* ppb = pp2 + ((size_t)b * 49 + pblk) * 256 + ci0;
#pragma unroll
    for (int pass = 0; pass < 4; ++pass) {
      int ci_l = pass * 16 + cq;
      float4 v = *(const float4*)&xb[(size_t)ci_l * NPIX + pq * 4];
      t[ci_l][pq * 4 + 0] = f2bf(v.x);
      t[ci_l][pq * 4 + 1] = f2bf(v.y);
      t[ci_l][pq * 4 + 2] = f2bf(v.z);
      t[ci_l][pq * 4 + 3] = f2bf(v.w);
      // fused pooling partial: sum this thread's 4 fp32 values, reduce over pq group
      float s = v.x + v.y + v.z + v.w;
      s += __shfl_xor(s, 1);
      s += __shfl_xor(s, 2);
      s += __shfl_xor(s, 4);
      s += __shfl_xor(s, 8);
      if (pq == 0) ppb[ci_l] = s;
    }
    __syncthreads();
    int cio = (tid & 31) * 2, jo = tid >> 5;
#pragma unroll
    for (int pass = 0; pass < 8; ++pass) {
      int jj = pass * 8 + jo;
      int p = p0 + jj;
      int h = p / 56, w = p % 56;
      int row = (h + 1) * PH + (w + 1);
      unsigned int v = (unsigned int)t[cio][jj] | ((unsigned int)t[cio + 1][jj] << 16);
      *(unsigned int*)(xT + ((size_t)b * PPIX + row) * NCH + ci0 + cio) = v;
    }
  } else if (blk < 6272 + 144) {
    // ---- weight tiles ----
    int wblk = blk - 6272;
    int stage = wblk >> 1, half = wblk & 1;
    int tap = stage % 9, cs = stage / 9;
    unsigned short* dst = wt + (size_t)stage * 8192 + half * 4096;
#pragma unroll
    for (int e8 = 0; e8 < 16; ++e8) {
      int j = e8 * 256 + tid;           // 0..4095 over [128co][32ci]
      int ci_l = j & 31, co_l = j >> 5;
      int slot = ci_l >> 3, e = ci_l & 7;
      int slot_g = slot ^ ((co_l >> 1) & 3);        // inverse swizzle at source
      int co = half * 128 + co_l, ci = cs * 32 + slot_g * 8 + e;
      dst[j] = f2bf(cw[((size_t)co * 256 + ci) * 9 + tap]);
    }
  } else {
    // ---- zero xT borders ----
    int g = (blk - 6416) * 256 + tid;    // uint index, < 933888
    int b = g / 29184;                   // 228 border rows * 128 uints
    int rem = g - b * 29184;
    int ridx = rem >> 7, ui = rem & 127;
    int row;
    if (ridx < 58)       row = ridx;
    else if (ridx < 116) row = 57 * 58 + (ridx - 58);
    else { int r2 = ridx - 116; row = (1 + (r2 >> 1)) * 58 + ((r2 & 1) ? 57 : 0); }
    ((unsigned int*)(xT + ((size_t)b * PPIX + row) * NCH))[ui] = 0;
  }
}

// ---------------- head: rmsnorm + phi + sigmoids + sinkhorn -> 3 scalars per batch ----------------
__global__ __launch_bounds__(256) void head_k(const float* __restrict__ pp2,
    const float* __restrict__ phi_w, const float* __restrict__ phi_b,
    const float* __restrict__ rms_w, const float* __restrict__ a_pre,
    const float* __restrict__ a_post, const float* __restrict__ a_res,
    float* __restrict__ scales) {
  int b = blockIdx.x;
  int t = threadIdx.x;
  __shared__ float red[4];
  __shared__ float coeff[24];
  float s = 0;
  for (int ch = 0; ch < 49; ++ch) s += pp2[((size_t)b * 49 + ch) * 256 + t];
  float pooled = s * (1.0f / (float)NPIX);
  float v = pooled * pooled;
#pragma unroll
  for (int off = 32; off; off >>= 1) v += __shfl_down(v, off);
  if ((t & 63) == 0) red[t >> 6] = v;
  __syncthreads();
  float ms = (red[0] + red[1] + red[2] + red[3]) * (1.0f / 256.0f);
  float inv = rsqrtf(ms + 1e-20f);
  __syncthreads();
  for (int o = 0; o < 24; ++o) {
    float ws_ = 0;
#pragma unroll
    for (int i = 0; i < 4; ++i) ws_ += phi_w[(size_t)o * 1024 + i * 256 + t] * rms_w[i * 256 + t];
    float c = pooled * ws_;
#pragma unroll
    for (int off = 32; off; off >>= 1) c += __shfl_down(c, off);
    if ((t & 63) == 0) red[t >> 6] = c;
    __syncthreads();
    if (t == 0) coeff[o] = inv * (red[0] + red[1] + red[2] + red[3]) + phi_b[o];
    __syncthreads();
  }
  if (t == 0) {
    float ap = a_pre[0], apo = a_post[0], ar = a_res[0];
    float spre = 0, psum = 0;
#pragma unroll
    for (int i = 0; i < 4; ++i) {
      spre += 1.0f / (1.0f + expf(-ap * coeff[i]));
      psum += 2.0f / (1.0f + expf(-apo * coeff[4 + i]));
    }
    float M[4][4];
#pragma unroll
    for (int i = 0; i < 4; ++i)
#pragma unroll
      for (int j = 0; j < 4; ++j) M[i][j] = expf(ar * coeff[8 + i * 4 + j]);
    for (int it = 0; it < 20; ++it) {
#pragma unroll
      for (int i = 0; i < 4; ++i) {
        float rs = M[i][0] + M[i][1] + M[i][2] + M[i][3];
        float rr = 1.0f / rs;
        M[i][0] *= rr; M[i][1] *= rr; M[i][2] *= rr; M[i][3] *= rr;
      }
#pragma unroll
      for (int j = 0; j < 4; ++j) {
        float cs2 = M[0][j] + M[1][j] + M[2][j] + M[3][j];
        float rr = 1.0f / cs2;
        M[0][j] *= rr; M[1][j] *= rr; M[2][j] *= rr; M[3][j] *= rr;
      }
    }
    float r = 0.25f * (M[0][0] + M[1][1] + M[2][2] + M[3][3]);
    float pm = 0.25f * psum;
    scales[b * 4 + 0] = r;          // on x
    scales[b * 4 + 1] = pm * spre;  // on conv(x)
    scales[b * 4 + 2] = pm;         // on conv_b
  }
}

// ---------------- conv implicit GEMM: R12/R14 kernel VERBATIM (post-timing verified).
// 128co x 128col tile, 256 thr / 4 waves (2M x 2N), acc 64 + arch 64 = 128 regs/thread
// -> launch_bounds(256,4): 4 waves/SIMD = 4 co-resident blocks/CU (16 waves/CU).
// Grid 1568 with XCD chunk swizzle; co-half pairs adjacent -> B-tile L2 reuse.
// Simple 2-phase dbuf K-loop; inter-block wave overlap supplies pipelining (R11/R12: +15%).
// XOR bank swizzle (0 conflicts). ----------------
__global__ __launch_bounds__(256, 4) void conv_k(
    const unsigned short* __restrict__ xT, const unsigned short* __restrict__ wt,
    const float* __restrict__ x, const float* __restrict__ conv_b,
    const float* __restrict__ scales, float* __restrict__ out) {
  // per buffer: [A 8 KB: 128co x 32ci][B 8 KB: 128col x 32ci]
  __shared__ __align__(16) char lds_[2][16384];
  // XCD chunk swizzle: hw bid -> work id so each XCD owns contiguous work
  const int wgid = (blockIdx.x & 7) * 196 + (blockIdx.x >> 3);
  const int colblk = wgid >> 1;       // 784
  const int coh = wgid & 1;           // co half
  const int tid = threadIdx.x;
  const int wv = tid >> 6, l = tid & 63;
  const int wm = wv >> 1, wn = wv & 1;

  // ---- B staging lane addresses (2 gloads: 64 cols x 64B each round) ----
  const char* laneB0;
  const char* laneB1;
  {
    const char* lb[2];
#pragma unroll
    for (int gi = 0; gi < 2; ++gi) {
      int col_local = gi * 64 + wv * 16 + (l >> 2);
      int col = colblk * 128 + col_local;
      int bb = col / NPIX, pix = col - bb * NPIX;
      int prow = (pix / 56 + 1) * PH + (pix % 56 + 1);
      int slot_g = (l & 3) ^ ((col_local >> 1) & 3);
      lb[gi] = (const char*)xT + ((size_t)bb * PPIX + prow) * 512 + slot_g * 16;
    }
    laneB0 = lb[0]; laneB1 = lb[1];
  }
  const char* wtb = (const char*)wt + coh * 8192;
  // tap -> padded-row byte shift
  const int tapsh[9] = {-59 * 512, -58 * 512, -57 * 512, -512, 0, 512, 57 * 512, 58 * 512, 59 * 512};

  // stage K32-stage ST into buffer STG: A 2 gloads + B 2 gloads per thread
#define STAGE(STG, ST) do {                                                 \
    int st_ = (ST); int cs_ = st_ / 9, tap_ = st_ - cs_ * 9;                \
    int sh_ = tapsh[tap_] + cs_ * 64;                                       \
    const char* as_ = wtb + (size_t)st_ * 16384 + wv * 1024 + l * 16;       \
    char* da_ = (STG) + wv * 1024;                                          \
    gload_lds16(as_,        da_);                                           \
    gload_lds16(as_ + 4096, da_ + 4096);                                    \
    char* db_ = (STG) + 8192 + wv * 1024;                                   \
    gload_lds16(laneB0 + sh_, db_);                                         \
    gload_lds16(laneB1 + sh_, db_ + 4096);                                  \
  } while (0)

  // ---- fragment LDS byte offsets (bank-swizzled: slot ^= (row>>1)&3) ----
  int aoff[4], boff[4];
#pragma unroll
  for (int m = 0; m < 4; ++m) {
    int row = wm * 64 + m * 16 + (l & 15);
    aoff[m] = row * 64 + ((((l >> 4) ^ (row >> 1)) & 3) << 4);
  }
#pragma unroll
  for (int n = 0; n < 4; ++n) {
    int row = wn * 64 + n * 16 + (l & 15);
    boff[n] = 8192 + row * 64 + ((((l >> 4) ^ (row >> 1)) & 3) << 4);
  }

  f32x4 acc[4][4];
#pragma unroll
  for (int m = 0; m < 4; ++m)
#pragma unroll
    for (int n = 0; n < 4; ++n) acc[m][n] = (f32x4){0.f, 0.f, 0.f, 0.f};

  // ---- prologue: stage stage-0 into buf0, drain, barrier ----
  STAGE(&lds_[0][0], 0);
  asm volatile("s_waitcnt vmcnt(0)" ::: "memory");
  __builtin_amdgcn_s_barrier();

  for (int s = 0; s < 72; ++s) {
    const char* Ab = &lds_[s & 1][0];
    char* stg = &lds_[(s + 1) & 1][0];
    bf16x8 af[4], bfr[4];
#pragma unroll
    for (int m = 0; m < 4; ++m) af[m] = *(const bf16x8*)(Ab + aoff[m]);
#pragma unroll
    for (int n = 0; n < 4; ++n) bfr[n] = *(const bf16x8*)(Ab + boff[n]);
    if (s < 71) STAGE(stg, s + 1);            // prefetch under this stage's MFMA
    __builtin_amdgcn_s_setprio(1);
#pragma unroll
    for (int m = 0; m < 4; ++m)
#pragma unroll
      for (int n = 0; n < 4; ++n)
        acc[m][n] = __builtin_amdgcn_mfma_f32_16x16x32_bf16(af[m], bfr[n], acc[m][n], 0, 0, 0);
    __builtin_amdgcn_s_setprio(0);
    if (s < 71) {
      asm volatile("s_waitcnt vmcnt(0)" ::: "memory");  // drain covered by sibling blocks
      __builtin_amdgcn_s_barrier();
    }
  }
#undef STAGE

  // ---- epilogue: out = sX*x + sY*conv + sB*conv_b ----
  const int lc = l & 15, lg = l >> 4;
  float sXn[4], sYn[4], sBn[4];
  size_t obase[4];
#pragma unroll
  for (int n = 0; n < 4; ++n) {
    int col = colblk * 128 + wn * 64 + n * 16 + lc;
    int bb = col / NPIX, pix = col - bb * NPIX;
    sXn[n] = scales[bb * 4 + 0];
    sYn[n] = scales[bb * 4 + 1];
    sBn[n] = scales[bb * 4 + 2];
    obase[n] = (size_t)bb * NCH * NPIX + pix;
  }
#pragma unroll
  for (int m = 0; m < 4; ++m) {
#pragma unroll
    for (int j = 0; j < 4; ++j) {
      int co = coh * 128 + wm * 64 + m * 16 + lg * 4 + j;
      float cbv = conv_b[co];
      size_t cooff = (size_t)co * NPIX;
#pragma unroll
      for (int n = 0; n < 4; ++n) {
        size_t idx = obase[n] + cooff;
        out[idx] = sXn[n] * x[idx] + sYn[n] * acc[m][n][j] + sBn[n] * cbv;
      }
    }
  }
}

extern "C" void kernel_launch(void* const* d_in, const int* in_sizes, int n_in,
                              void* d_out, int out_size, void* d_ws, size_t ws_size,
                              hipStream_t stream) {
  const float* x      = (const float*)d_in[0];
  const float* phi_w  = (const float*)d_in[1];
  const float* phi_b  = (const float*)d_in[2];
  const float* rms_w  = (const float*)d_in[3];
  const float* a_pre  = (const float*)d_in[4];
  const float* a_post = (const float*)d_in[5];
  const float* a_res  = (const float*)d_in[6];
  const float* conv_w = (const float*)d_in[7];
  const float* conv_b = (const float*)d_in[8];
  float* out = (float*)d_out;

  char* ws = (char*)d_ws;
  unsigned short* xT = (unsigned short*)ws;
  const size_t XT_BYTES = (size_t)NB * PPIX * NCH * 2;            // 55,115,776
  float* pp2 = (float*)(ws + XT_BYTES);
  const size_t PP_BYTES = (size_t)NB * 49 * 256 * 4;              // 1,605,632
  float* scales = (float*)(ws + XT_BYTES + PP_BYTES);
  unsigned short* wt = (unsigned short*)(ws + XT_BYTES + PP_BYTES + 512);

  pre_k<<<dim3(6272 + 144 + 3648), dim3(256), 0, stream>>>(x, conv_w, wt, xT, pp2);
  head_k<<<dim3(NB), dim3(256), 0, stream>>>(pp2, phi_w, phi_b, rms_w, a_pre, a_post, a_res, scales);
  conv_k<<<dim3(1568), dim3(256), 0, stream>>>(xT, wt, x, conv_b, scales, out);
}